// Round 1
// baseline (218.076 us; speedup 1.0000x reference)
//
#include <hip/hip_runtime.h>

// Problem constants (fixed-shape problem)
#define BB 4
#define CC 16
#define KK 16
#define HWP (512 * 512)
#define TILE 2048
#define THREADS 256
#define PPT (TILE / THREADS)   // 8 pixels/thread in phase 1
#define JITERS (TILE / 16)     // 128 iters/thread in phase 2

__device__ __forceinline__ float fmaxf_(float a, float b) { return a > b ? a : b; }

__global__ __launch_bounds__(THREADS) void disc_partial_kernel(
    const float* __restrict__ emb, const int* __restrict__ masks,
    float* __restrict__ ws_cnt, float* __restrict__ ws_sum, float* __restrict__ ws_sq)
{
    __shared__ unsigned short bits[TILE];
    const int tid = threadIdx.x;
    const int tiles_per_b = HWP / TILE;
    const int b = blockIdx.x / tiles_per_b;
    const int tile = blockIdx.x % tiles_per_b;
    const size_t tile0 = (size_t)tile * TILE;

    // ---- phase 1: pack 16 mask planes into per-pixel bitmask in LDS ----
    const int* mbase = masks + (size_t)b * KK * HWP + tile0;
    #pragma unroll
    for (int i = 0; i < PPT; ++i) {
        int pl = tid + i * THREADS;
        unsigned v = 0;
        #pragma unroll
        for (int k = 0; k < KK; ++k) {
            v |= (mbase[(size_t)k * HWP + pl] > 0 ? 1u : 0u) << k;
        }
        bits[pl] = (unsigned short)v;
    }
    __syncthreads();

    // ---- phase 2: each 16-thread group owns one channel, streams the tile ----
    const int c = tid >> 4;
    const int l = tid & 15;
    const float* ebase = emb + ((size_t)b * CC + c) * HWP + tile0;

    float s[KK], q[KK], cn[KK];
    #pragma unroll
    for (int k = 0; k < KK; ++k) { s[k] = 0.f; q[k] = 0.f; cn[k] = 0.f; }
    const bool count_lane = (c == 0);

    for (int j = 0; j < JITERS; ++j) {
        int pl = l + j * 16;
        float e = ebase[pl];
        float e2 = e * e;
        unsigned v = (unsigned)bits[pl];
        #pragma unroll
        for (int k = 0; k < KK; ++k) {
            float fm = (float)((v >> k) & 1u);
            s[k] = fmaf(fm, e, s[k]);
            q[k] = fmaf(fm, e2, q[k]);
            if (count_lane) cn[k] += fm;
        }
    }

    // ---- butterfly reduce across the 16-lane group; lane l keeps k==l ----
    float out_s = 0.f, out_q = 0.f, out_c = 0.f;
    #pragma unroll
    for (int k = 0; k < KK; ++k) {
        float ts = s[k], tq = q[k], tc = cn[k];
        #pragma unroll
        for (int d = 8; d >= 1; d >>= 1) {
            ts += __shfl_xor(ts, d, 64);
            tq += __shfl_xor(tq, d, 64);
            tc += __shfl_xor(tc, d, 64);
        }
        if (l == k) { out_s = ts; out_q = tq; out_c = tc; }
    }
    atomicAdd(&ws_sum[((size_t)b * KK + l) * CC + c], out_s);
    atomicAdd(&ws_sq [((size_t)b * KK + l) * CC + c], out_q);
    if (c == 0) atomicAdd(&ws_cnt[b * KK + l], out_c);
}

__global__ __launch_bounds__(256) void disc_finalize_kernel(
    const float* __restrict__ ws_cnt, const float* __restrict__ ws_sum,
    const float* __restrict__ ws_sq, float* __restrict__ out)
{
    __shared__ float means[BB][KK][CC];
    __shared__ float partial[BB];
    const int tid = threadIdx.x;
    const int b = tid >> 6;       // one wave per batch
    const int lane = tid & 63;

    const float DELTA_PULL = 0.5f;
    const float DELTA_PUSH = 1.5f;
    const float EPS = 1e-6f;

    float cntk = 0.f;
    bool valid = false;
    float pull_k = 0.f;
    if (lane < KK) {
        int k = lane;
        cntk = ws_cnt[b * KK + k];
        valid = cntk > 0.f;
        float safe = fmaxf_(cntk, 1.f);
        float acc_sq = 0.f, acc_ss = 0.f;
        #pragma unroll
        for (int c = 0; c < CC; ++c) {
            float sv = ws_sum[(b * KK + k) * CC + c];
            means[b][k][c] = sv / safe;
            acc_sq += ws_sq[(b * KK + k) * CC + c];
            acc_ss += sv * sv;
        }
        if (valid) pull_k = (acc_sq - acc_ss / cntk) / (cntk + EPS);
    }

    unsigned long long bal = __ballot(lane < KK && valid);
    float M = (float)__popcll(bal);

    float ps = pull_k;
    #pragma unroll
    for (int d = 32; d >= 1; d >>= 1) ps += __shfl_xor(ps, d, 64);
    float pull_b = ps / fmaxf_(M, 1.f);

    __syncthreads();   // means written by this wave; barrier harmless

    float push = 0.f;
    for (int t = lane; t < KK * KK; t += 64) {
        int i = t >> 4, j = t & 15;
        if (i < j && ((bal >> i) & 1ull) && ((bal >> j) & 1ull)) {
            float d2 = 1e-12f;
            #pragma unroll
            for (int c = 0; c < CC; ++c) {
                float df = means[b][i][c] - means[b][j][c];
                d2 = fmaf(df, df, d2);
            }
            float dist = sqrtf(d2);
            float h = fmaxf_(DELTA_PUSH - dist, 0.f);
            push += h * h;
        }
    }
    #pragma unroll
    for (int d = 32; d >= 1; d >>= 1) push += __shfl_xor(push, d, 64);

    if (lane == 0) {
        float npairs = M * (M - 1.f) * 0.5f;
        float push_b = (M > 1.f) ? push / fmaxf_(npairs, 1.f) : 0.f;
        partial[b] = DELTA_PULL * pull_b + push_b;
    }
    __syncthreads();
    if (tid == 0) {
        out[0] = (partial[0] + partial[1] + partial[2] + partial[3]) * 0.25f;
    }
}

extern "C" void kernel_launch(void* const* d_in, const int* in_sizes, int n_in,
                              void* d_out, int out_size, void* d_ws, size_t ws_size,
                              hipStream_t stream) {
    const float* emb = (const float*)d_in[0];
    const int* masks = (const int*)d_in[1];
    float* ws = (float*)d_ws;
    float* ws_cnt = ws;               // 64 floats
    float* ws_sum = ws + 64;          // 1024 floats
    float* ws_sq  = ws + 64 + 1024;   // 1024 floats

    hipMemsetAsync(d_ws, 0, (64 + 1024 + 1024) * sizeof(float), stream);

    dim3 grid(BB * (HWP / TILE));
    disc_partial_kernel<<<grid, THREADS, 0, stream>>>(emb, masks, ws_cnt, ws_sum, ws_sq);
    disc_finalize_kernel<<<1, 256, 0, stream>>>(ws_cnt, ws_sum, ws_sq, (float*)d_out);
}